// Round 3
// baseline (751.677 us; speedup 1.0000x reference)
//
#include <hip/hip_runtime.h>

// FSAS slab pipeline, 4 slabs of 64 rows, bf16 intermediates:
//   k2: affine(kv) + 1x1 conv 64->384 -> hid bf16 slab (66 rows incl. halo)
//       v3: x row in VGPRs (xp[64]), 3x out-chunk-64, zero LDS, x read 2x not 12x
//   k3: grouped 3x3 -> qkv bf16 slab, PATCHIFIED [ch][patch(256)][64]
//   kC: per-patch circular conv (q,k in VGPRs) + LN + *v + proj 128->64 -> out
// Workspace:
//   kv  fp32 @ 0      (512)
//   whT fp32 @ 512    (24576)  whT[c*384+o] = w_hidden[o][c]
//   wpT fp32 @ 25088  (8192)   wpT[c*64+o]  = w_proj[o][c]
//   hid bf16 @ float-ofs 40960 : [4][384][66][256]  (51.9 MB)
//   qkv bf16 after hid          : [4][384][256][64]  (50.3 MB)
// Total 102,400,000 B = 97.66 MiB (< proven 99.15 MiB).

#define HW    65536
#define SLAB  64
#define HROWS 66
#define HSZ2  (HROWS*256)   // bf16 elems per (b,ch) hid plane
#define QS    16384         // bf16 elems per (b,ch) qkv plane (256 patches * 64)

__device__ __forceinline__ unsigned short f2bf(float f) {
    unsigned u = __float_as_uint(f);
    u += 0x7FFFu + ((u >> 16) & 1u);       // RNE
    return (unsigned short)(u >> 16);
}
__device__ __forceinline__ float bflo(unsigned u) { return __uint_as_float(u << 16); }
__device__ __forceinline__ float bfhi(unsigned u) { return __uint_as_float(u & 0xFFFF0000u); }

__global__ void k_prep(const float* __restrict__ prior, const float* __restrict__ wk,
                       const float* __restrict__ wh, const float* __restrict__ wp,
                       float* __restrict__ kv, float* __restrict__ whT, float* __restrict__ wpT) {
    int t = blockIdx.x * 256 + threadIdx.x;
    if (t < 512) {
        int b = t >> 7, k = t & 127;
        const float* p = prior + b * 192;
        const float* w = wk + k * 192;
        float s = 0.f;
        for (int f = 0; f < 192; ++f) s = fmaf(p[f], w[f], s);
        kv[t] = s;
        return;
    }
    t -= 512;
    if (t < 24576) {
        int c = t / 384, o = t - c * 384;
        whT[t] = wh[o * 64 + c];
        return;
    }
    t -= 24576;
    int c = t >> 6, o = t & 63;
    wpT[t] = wp[o * 128 + c];
}

// v3: block = (row, out-half, b); thread = pixel. x row loaded to VGPRs once,
// affine applied in regs; 3 chunks of 64 out-ch, acc[64], weights via wave-
// uniform scalar loads. No LDS, no barriers, no global loads in the FMA loop.
__global__ __launch_bounds__(256, 3) void k2_hidden(const float* __restrict__ x,
    const float* __restrict__ whT, const float* __restrict__ kv,
    unsigned short* __restrict__ hid, int r0) {
    int row = blockIdx.x;            // 0..65
    int px  = threadIdx.x;           // 0..255
    int half = blockIdx.y;           // 0..1  (192 out-ch each)
    int b = blockIdx.z;
    int g = r0 - 1 + row;
    unsigned short* hb = hid + ((size_t)(b * 384 + half * 192)) * HSZ2
                         + row * 256 + px;
    if (g < 0 || g > 255) {
        #pragma unroll 8
        for (int j = 0; j < 192; ++j) hb[(size_t)j * HSZ2] = 0;
        return;
    }
    const float* xb = x + (size_t)b * 64 * HW + (size_t)g * 256 + px;
    const float* kv1 = kv + b * 128;
    const float* kv2 = kv1 + 64;
    float xp[64];
    #pragma unroll
    for (int c = 0; c < 64; ++c)
        xp[c] = fmaf(xb[(size_t)c * HW], kv1[c], kv2[c]);
    #pragma unroll
    for (int ch = 0; ch < 3; ++ch) {
        const float* wbase = whT + half * 192 + ch * 64;   // + c*384, wave-uniform
        float acc[64];
        #pragma unroll
        for (int j = 0; j < 64; ++j) acc[j] = 0.f;
        #pragma unroll 4
        for (int c = 0; c < 64; ++c) {
            float xv = xp[c];
            const float* wr = wbase + c * 384;             // scalar loads
            #pragma unroll
            for (int j = 0; j < 64; ++j)
                acc[j] = fmaf(wr[j], xv, acc[j]);
        }
        unsigned short* hc = hb + (size_t)(ch * 64) * HSZ2;
        #pragma unroll
        for (int j = 0; j < 64; ++j)
            hc[(size_t)j * HSZ2] = f2bf(acc[j]);
    }
}

// grouped 3x3 conv from bf16 hid -> bf16 qkv patchified [ch][patch][py*8+px]
__global__ __launch_bounds__(256) void k3_dw(const unsigned short* __restrict__ hid,
    const float* __restrict__ wdw, unsigned short* __restrict__ qkv) {
    __shared__ float sIn[2 * 18 * 66];
    int t = threadIdx.x;
    int bid = blockIdx.x;            // 16 tiles: tx 0..3 (x64 cols), ty 0..3 (x16 rows)
    int gl = blockIdx.y;             // 0..191
    int b = blockIdx.z;
    int tx = bid & 3, ty = bid >> 2;
    int x0 = tx * 64, y0 = ty * 16;
    const unsigned short* hbase = hid + ((size_t)(b * 384 + 2 * gl)) * HSZ2;
    for (int idx = t; idx < 2 * 18 * 66; idx += 256) {
        int chl = idx >= 1188;
        int rem = idx - chl * 1188;
        int row = rem / 66;
        int col = rem - row * 66;
        int gx = x0 + col - 1;
        float v = 0.f;
        if (gx >= 0 && gx < 256)
            v = bflo((unsigned)hbase[(size_t)chl * HSZ2 + (y0 + row) * 256 + gx]);
        sIn[idx] = v;
    }
    __syncthreads();
    int og = 2 * gl;
    float w0[18], w1[18];
    #pragma unroll
    for (int i = 0; i < 18; ++i) {
        w0[i] = wdw[(size_t)og * 18 + i];
        w1[i] = wdw[(size_t)(og + 1) * 18 + i];
    }
    unsigned short* q0 = qkv + ((size_t)(b * 384 + og)) * QS;
    #pragma unroll
    for (int pp = 0; pp < 2; ++pp) {
        int ly = pp * 8 + (t >> 5);                  // 0..15
        int lxp = (t & 31) * 2;                      // even col in tile
        float a[2][2];                               // [px][out-ch]
        #pragma unroll
        for (int px = 0; px < 2; ++px) {
            float s0 = 0.f, s1 = 0.f;
            #pragma unroll
            for (int i = 0; i < 2; ++i)
                #pragma unroll
                for (int ky = 0; ky < 3; ++ky)
                    #pragma unroll
                    for (int kx = 0; kx < 3; ++kx) {
                        float v = sIn[i * 1188 + (ly + ky) * 66 + (lxp + px + kx)];
                        s0 = fmaf(w0[i * 9 + ky * 3 + kx], v, s0);
                        s1 = fmaf(w1[i * 9 + ky * 3 + kx], v, s1);
                    }
            a[px][0] = s0; a[px][1] = s1;
        }
        int row = y0 + ly;                           // slab row 0..63
        int gx = x0 + lxp;
        int patch = (row >> 3) * 32 + (gx >> 3);     // 0..255
        int off = patch * 64 + (row & 7) * 8 + (gx & 7);   // even
        ((unsigned*)(q0 + off))[0] =
            (unsigned)f2bf(a[0][0]) | ((unsigned)f2bf(a[1][0]) << 16);
        ((unsigned*)(q0 + QS + off))[0] =
            (unsigned)f2bf(a[0][1]) | ((unsigned)f2bf(a[1][1]) << 16);
    }
}

// Fused per-patch: circular conv (q,k in regs) + LN(128) + *v + proj 128->64.
// Thread t: channel c = t&127, py-half pyh = t>>7.
// v2 dataflow: 3 barriers, no serial phase.
//   P0 conv -> sC[c][68] (float4 writes, transposed)
//   P1 reduce over c: (q4,px) mapping, 4 partials per pixel live in ONE wave,
//      combined with 2x shfl_xor -> sMu/sRstd (no sRed arrays, no t<64 phase)
//   P3 normalize from acc regs -> tvv to sT[pix][132] (aliases sC)
//   P4 proj: ds_read_b128 over channels (4/instr), weights via SGPR
__global__ __launch_bounds__(256, 2) void kC_patch(const unsigned short* __restrict__ qkv,
    const float* __restrict__ wpT, const float* __restrict__ lnw,
    const float* __restrict__ lnb, float* __restrict__ outp, int r0) {
    __shared__ __align__(16) float sBuf[128 * 68];   // P0/P1: sC[c][68]; P3/P4: sT[pix][132]
    __shared__ __align__(16) float sMu[64];
    __shared__ __align__(16) float sRstd[64];
    int t = threadIdx.x;
    int p = blockIdx.x;              // slab-local patch 0..255
    int b = blockIdx.y;
    int c = t & 127;
    int pyh = t >> 7;

    const uint4* gq = (const uint4*)(qkv + ((size_t)(b * 384 + c)) * QS + p * 64);
    const uint4* gk = (const uint4*)(qkv + ((size_t)(b * 384 + 128 + c)) * QS + p * 64);
    float q[64], k[64];
    #pragma unroll
    for (int f = 0; f < 8; ++f) {                     // 8 bf16 per uint4
        uint4 u = gq[f];
        q[f * 8 + 0] = bflo(u.x); q[f * 8 + 1] = bfhi(u.x);
        q[f * 8 + 2] = bflo(u.y); q[f * 8 + 3] = bfhi(u.y);
        q[f * 8 + 4] = bflo(u.z); q[f * 8 + 5] = bfhi(u.z);
        q[f * 8 + 6] = bflo(u.w); q[f * 8 + 7] = bfhi(u.w);
    }
    // k rows pre-rotated: reg row s = global row (s + 4*pyh)&7 ; one uint4 per row
    #pragma unroll
    for (int s = 0; s < 8; ++s) {
        int r = (s + 4 * pyh) & 7;
        uint4 u = ((const uint4*)gk)[r];
        k[s * 8 + 0] = bflo(u.x); k[s * 8 + 1] = bfhi(u.x);
        k[s * 8 + 2] = bflo(u.y); k[s * 8 + 3] = bfhi(u.y);
        k[s * 8 + 4] = bflo(u.z); k[s * 8 + 5] = bfhi(u.z);
        k[s * 8 + 6] = bflo(u.w); k[s * 8 + 7] = bfhi(u.w);
    }
    float acc[4][8];
    #pragma unroll
    for (int it = 0; it < 4; ++it)
        #pragma unroll
        for (int px = 0; px < 8; ++px) acc[it][px] = 0.f;
    #pragma unroll
    for (int iy = 0; iy < 8; ++iy)
        #pragma unroll
        for (int ix = 0; ix < 8; ++ix) {
            float qv = q[iy * 8 + ix];
            #pragma unroll
            for (int it = 0; it < 4; ++it) {
                int ks = (it - iy) & 7;              // compile-time
                #pragma unroll
                for (int px = 0; px < 8; ++px)
                    acc[it][px] = fmaf(qv, k[ks * 8 + ((px - ix) & 7)], acc[it][px]);
            }
        }
    // transposed conv scratch: sC[c][pix], pad 68 (row stride 272 B, 16B-aligned)
    #pragma unroll
    for (int it = 0; it < 4; ++it) {
        int pix0 = pyh * 32 + it * 8;
        *(float4*)&sBuf[c * 68 + pix0] =
            make_float4(acc[it][0], acc[it][1], acc[it][2], acc[it][3]);
        *(float4*)&sBuf[c * 68 + pix0 + 4] =
            make_float4(acc[it][4], acc[it][5], acc[it][6], acc[it][7]);
    }
    // prefetch v (32 bf16 = 4 uint4)
    const uint4* gv = (const uint4*)(qkv + ((size_t)(b * 384 + 256 + c)) * QS
                                     + p * 64 + pyh * 32);
    float vv[32];
    #pragma unroll
    for (int f = 0; f < 4; ++f) {
        uint4 u = gv[f];
        vv[f * 8 + 0] = bflo(u.x); vv[f * 8 + 1] = bfhi(u.x);
        vv[f * 8 + 2] = bflo(u.y); vv[f * 8 + 3] = bfhi(u.y);
        vv[f * 8 + 4] = bflo(u.z); vv[f * 8 + 5] = bfhi(u.z);
        vv[f * 8 + 6] = bflo(u.w); vv[f * 8 + 7] = bfhi(u.w);
    }
    float lw = lnw[c], lb = lnb[c];
    __syncthreads();

    // P1: per-pixel channel reduction. Wave w owns pixels w*16..w*16+15;
    // lane bits 4..5 = channel-quarter -> butterfly within the wave.
    {
        int q4 = (t >> 4) & 3;
        int px = (t & 15) | ((t >> 6) << 4);
        float s = 0.f, s2 = 0.f;
        #pragma unroll
        for (int j = 0; j < 32; ++j) {
            float v = sBuf[(q4 * 32 + j) * 68 + px];
            s += v;
            s2 = fmaf(v, v, s2);
        }
        s  += __shfl_xor(s, 16);   s2 += __shfl_xor(s2, 16);
        s  += __shfl_xor(s, 32);   s2 += __shfl_xor(s2, 32);
        if ((t & 48) == 0) {
            float mu = s * (1.f / 128.f);
            float var = s2 * (1.f / 128.f) - mu * mu;
            sMu[px] = mu;
            sRstd[px] = rsqrtf(var + 1e-5f);
        }
    }
    __syncthreads();
    // P3: normalize from acc regs, * v, stage tvv as sT[pix][132] (c contiguous)
    #pragma unroll
    for (int it = 0; it < 4; ++it) {
        int pix0 = pyh * 32 + it * 8;
        float4 ma = *(const float4*)&sMu[pix0];
        float4 mb = *(const float4*)&sMu[pix0 + 4];
        float4 ra = *(const float4*)&sRstd[pix0];
        float4 rb = *(const float4*)&sRstd[pix0 + 4];
        float mus[8] = {ma.x, ma.y, ma.z, ma.w, mb.x, mb.y, mb.z, mb.w};
        float rss[8] = {ra.x, ra.y, ra.z, ra.w, rb.x, rb.y, rb.z, rb.w};
        #pragma unroll
        for (int px = 0; px < 8; ++px) {
            float tv = fmaf((acc[it][px] - mus[px]) * rss[px], lw, lb)
                       * vv[it * 8 + px];
            sBuf[(pix0 + px) * 132 + c] = tv;
        }
    }
    __syncthreads();
    // P4: proj 128->64, tvv read as float4 (4 channels / ds_read_b128)
    {
        int px = t & 63;
        int og = __builtin_amdgcn_readfirstlane((t >> 6) * 16);
        float po[16];
        #pragma unroll
        for (int j = 0; j < 16; ++j) po[j] = 0.f;
        const float4* tb = (const float4*)&sBuf[px * 132];
        #pragma unroll 4
        for (int k4 = 0; k4 < 32; ++k4) {
            float4 tv = tb[k4];
            const float* w0 = wpT + (k4 * 4 + 0) * 64 + og;
            const float* w1 = wpT + (k4 * 4 + 1) * 64 + og;
            const float* w2 = wpT + (k4 * 4 + 2) * 64 + og;
            const float* w3 = wpT + (k4 * 4 + 3) * 64 + og;
            #pragma unroll
            for (int j = 0; j < 16; ++j)
                po[j] = fmaf(w0[j], tv.x,
                        fmaf(w1[j], tv.y,
                        fmaf(w2[j], tv.z,
                        fmaf(w3[j], tv.w, po[j]))));
        }
        int grow = r0 + (p >> 5) * 8 + (px >> 3);
        int gcol = (p & 31) * 8 + (px & 7);
        float* ob = outp + ((size_t)(b * 64 + og)) * HW + grow * 256 + gcol;
        #pragma unroll
        for (int j = 0; j < 16; ++j) ob[(size_t)j * HW] = po[j];
    }
}

extern "C" void kernel_launch(void* const* d_in, const int* in_sizes, int n_in,
                              void* d_out, int out_size, void* d_ws, size_t ws_size,
                              hipStream_t stream) {
    const float* x     = (const float*)d_in[0];
    const float* prior = (const float*)d_in[1];
    const float* wk    = (const float*)d_in[2];
    const float* wh    = (const float*)d_in[3];
    const float* wdw   = (const float*)d_in[4];
    const float* wp    = (const float*)d_in[5];
    const float* lnw   = (const float*)d_in[6];
    const float* lnb   = (const float*)d_in[7];
    float* out = (float*)d_out;
    float* ws  = (float*)d_ws;

    float* kv  = ws;
    float* whT = ws + 512;
    float* wpT = ws + 512 + 24576;
    unsigned short* hid = (unsigned short*)(ws + 40960);        // [4][384][66][256] bf16
    unsigned short* qkv = hid + (size_t)4 * 384 * HSZ2;         // [4][384][256][64] bf16

    k_prep<<<dim3(130), dim3(256), 0, stream>>>(prior, wk, wh, wp, kv, whT, wpT);
    for (int slab = 0; slab < 4; ++slab) {
        int r0 = slab * SLAB;
        k2_hidden<<<dim3(HROWS, 2, 4), dim3(256), 0, stream>>>(x, whT, kv, hid, r0);
        k3_dw<<<dim3(16, 192, 4), dim3(256), 0, stream>>>(hid, wdw, qkv);
        kC_patch<<<dim3(256, 4), dim3(256), 0, stream>>>(qkv, wpT, lnw, lnb, out, r0);
    }
}

// Round 4
// 706.411 us; speedup vs baseline: 1.0641x; 1.0641x over previous
//
#include <hip/hip_runtime.h>

// FSAS slab pipeline, 4 slabs of 64 rows, bf16 intermediates:
//   k2: affine(kv) + 1x1 conv 64->384 -> hid bf16 slab (66 rows incl. halo)
//       v4: c-outer loop, xv consumed immediately (no xp array -> no scratch),
//           4 out-quarters of 96, acc[96] static-indexed, 4 waves/SIMD
//   k3: grouped 3x3 -> qkv bf16 slab, PATCHIFIED [ch][patch(256)][64]
//   kC: per-patch circular conv (q,k in VGPRs) + LN + *v + proj 128->64 -> out
// Workspace:
//   kv  fp32 @ 0      (512)
//   whT fp32 @ 512    (24576)  whT[c*384+o] = w_hidden[o][c]
//   wpT fp32 @ 25088  (8192)   wpT[c*64+o]  = w_proj[o][c]
//   hid bf16 @ float-ofs 40960 : [4][384][66][256]  (51.9 MB)
//   qkv bf16 after hid          : [4][384][256][64]  (50.3 MB)
// Total 102,400,000 B = 97.66 MiB (< proven 99.15 MiB).

#define HW    65536
#define SLAB  64
#define HROWS 66
#define HSZ2  (HROWS*256)   // bf16 elems per (b,ch) hid plane
#define QS    16384         // bf16 elems per (b,ch) qkv plane (256 patches * 64)

__device__ __forceinline__ unsigned short f2bf(float f) {
    unsigned u = __float_as_uint(f);
    u += 0x7FFFu + ((u >> 16) & 1u);       // RNE
    return (unsigned short)(u >> 16);
}
__device__ __forceinline__ float bflo(unsigned u) { return __uint_as_float(u << 16); }
__device__ __forceinline__ float bfhi(unsigned u) { return __uint_as_float(u & 0xFFFF0000u); }

__global__ void k_prep(const float* __restrict__ prior, const float* __restrict__ wk,
                       const float* __restrict__ wh, const float* __restrict__ wp,
                       float* __restrict__ kv, float* __restrict__ whT, float* __restrict__ wpT) {
    int t = blockIdx.x * 256 + threadIdx.x;
    if (t < 512) {
        int b = t >> 7, k = t & 127;
        const float* p = prior + b * 192;
        const float* w = wk + k * 192;
        float s = 0.f;
        for (int f = 0; f < 192; ++f) s = fmaf(p[f], w[f], s);
        kv[t] = s;
        return;
    }
    t -= 512;
    if (t < 24576) {
        int c = t / 384, o = t - c * 384;
        whT[t] = wh[o * 64 + c];
        return;
    }
    t -= 24576;
    int c = t >> 6, o = t & 63;
    wpT[t] = wp[o * 128 + c];
}

// v4: block = (row, out-quarter, b); thread = pixel. c-outer runtime loop:
// load xv, affine, feed 96 FMAs (acc[96], static j index only -> registers).
// No LDS, no barriers, no arrays indexed by a runtime loop counter.
__global__ __launch_bounds__(256, 4) void k2_hidden(const float* __restrict__ x,
    const float* __restrict__ whT, const float* __restrict__ kv,
    unsigned short* __restrict__ hid, int r0) {
    int row = blockIdx.x;            // 0..65
    int px  = threadIdx.x;           // 0..255
    int qtr = blockIdx.y;            // 0..3  (96 out-ch each)
    int b = blockIdx.z;
    int g = r0 - 1 + row;
    unsigned short* hb = hid + ((size_t)(b * 384 + qtr * 96)) * HSZ2
                         + row * 256 + px;
    if (g < 0 || g > 255) {
        #pragma unroll 8
        for (int j = 0; j < 96; ++j) hb[(size_t)j * HSZ2] = 0;
        return;
    }
    const float* xb = x + (size_t)b * 64 * HW + (size_t)g * 256 + px;
    const float* kv1 = kv + b * 128;
    const float* kv2 = kv1 + 64;
    const float* wbase = whT + qtr * 96;    // + c*384, wave-uniform -> scalar loads
    float acc[96];
    #pragma unroll
    for (int j = 0; j < 96; ++j) acc[j] = 0.f;
    #pragma unroll 2
    for (int c = 0; c < 64; ++c) {
        float xv = fmaf(xb[(size_t)c * HW], kv1[c], kv2[c]);
        const float* wr = wbase + c * 384;
        #pragma unroll
        for (int j = 0; j < 96; ++j)
            acc[j] = fmaf(wr[j], xv, acc[j]);
    }
    #pragma unroll
    for (int j = 0; j < 96; ++j)
        hb[(size_t)j * HSZ2] = f2bf(acc[j]);
}

// grouped 3x3 conv from bf16 hid -> bf16 qkv patchified [ch][patch][py*8+px]
__global__ __launch_bounds__(256) void k3_dw(const unsigned short* __restrict__ hid,
    const float* __restrict__ wdw, unsigned short* __restrict__ qkv) {
    __shared__ float sIn[2 * 18 * 66];
    int t = threadIdx.x;
    int bid = blockIdx.x;            // 16 tiles: tx 0..3 (x64 cols), ty 0..3 (x16 rows)
    int gl = blockIdx.y;             // 0..191
    int b = blockIdx.z;
    int tx = bid & 3, ty = bid >> 2;
    int x0 = tx * 64, y0 = ty * 16;
    const unsigned short* hbase = hid + ((size_t)(b * 384 + 2 * gl)) * HSZ2;
    for (int idx = t; idx < 2 * 18 * 66; idx += 256) {
        int chl = idx >= 1188;
        int rem = idx - chl * 1188;
        int row = rem / 66;
        int col = rem - row * 66;
        int gx = x0 + col - 1;
        float v = 0.f;
        if (gx >= 0 && gx < 256)
            v = bflo((unsigned)hbase[(size_t)chl * HSZ2 + (y0 + row) * 256 + gx]);
        sIn[idx] = v;
    }
    __syncthreads();
    int og = 2 * gl;
    float w0[18], w1[18];
    #pragma unroll
    for (int i = 0; i < 18; ++i) {
        w0[i] = wdw[(size_t)og * 18 + i];
        w1[i] = wdw[(size_t)(og + 1) * 18 + i];
    }
    unsigned short* q0 = qkv + ((size_t)(b * 384 + og)) * QS;
    #pragma unroll
    for (int pp = 0; pp < 2; ++pp) {
        int ly = pp * 8 + (t >> 5);                  // 0..15
        int lxp = (t & 31) * 2;                      // even col in tile
        float a[2][2];                               // [px][out-ch]
        #pragma unroll
        for (int px = 0; px < 2; ++px) {
            float s0 = 0.f, s1 = 0.f;
            #pragma unroll
            for (int i = 0; i < 2; ++i)
                #pragma unroll
                for (int ky = 0; ky < 3; ++ky)
                    #pragma unroll
                    for (int kx = 0; kx < 3; ++kx) {
                        float v = sIn[i * 1188 + (ly + ky) * 66 + (lxp + px + kx)];
                        s0 = fmaf(w0[i * 9 + ky * 3 + kx], v, s0);
                        s1 = fmaf(w1[i * 9 + ky * 3 + kx], v, s1);
                    }
            a[px][0] = s0; a[px][1] = s1;
        }
        int row = y0 + ly;                           // slab row 0..63
        int gx = x0 + lxp;
        int patch = (row >> 3) * 32 + (gx >> 3);     // 0..255
        int off = patch * 64 + (row & 7) * 8 + (gx & 7);   // even
        ((unsigned*)(q0 + off))[0] =
            (unsigned)f2bf(a[0][0]) | ((unsigned)f2bf(a[1][0]) << 16);
        ((unsigned*)(q0 + QS + off))[0] =
            (unsigned)f2bf(a[0][1]) | ((unsigned)f2bf(a[1][1]) << 16);
    }
}

// Fused per-patch: circular conv (q,k in regs) + LN(128) + *v + proj 128->64.
// Thread t: channel c = t&127, py-half pyh = t>>7.
// v2 dataflow: 3 barriers, no serial phase.
//   P0 conv -> sC[c][68] (float4 writes, transposed)
//   P1 reduce over c: (q4,px) mapping, 4 partials per pixel live in ONE wave,
//      combined with 2x shfl_xor -> sMu/sRstd (no sRed arrays, no t<64 phase)
//   P3 normalize from acc regs -> tvv to sT[pix][132] (aliases sC)
//   P4 proj: ds_read_b128 over channels (4/instr), weights via SGPR
__global__ __launch_bounds__(256, 2) void kC_patch(const unsigned short* __restrict__ qkv,
    const float* __restrict__ wpT, const float* __restrict__ lnw,
    const float* __restrict__ lnb, float* __restrict__ outp, int r0) {
    __shared__ __align__(16) float sBuf[128 * 68];   // P0/P1: sC[c][68]; P3/P4: sT[pix][132]
    __shared__ __align__(16) float sMu[64];
    __shared__ __align__(16) float sRstd[64];
    int t = threadIdx.x;
    int p = blockIdx.x;              // slab-local patch 0..255
    int b = blockIdx.y;
    int c = t & 127;
    int pyh = t >> 7;

    const uint4* gq = (const uint4*)(qkv + ((size_t)(b * 384 + c)) * QS + p * 64);
    const uint4* gk = (const uint4*)(qkv + ((size_t)(b * 384 + 128 + c)) * QS + p * 64);
    float q[64], k[64];
    #pragma unroll
    for (int f = 0; f < 8; ++f) {                     // 8 bf16 per uint4
        uint4 u = gq[f];
        q[f * 8 + 0] = bflo(u.x); q[f * 8 + 1] = bfhi(u.x);
        q[f * 8 + 2] = bflo(u.y); q[f * 8 + 3] = bfhi(u.y);
        q[f * 8 + 4] = bflo(u.z); q[f * 8 + 5] = bfhi(u.z);
        q[f * 8 + 6] = bflo(u.w); q[f * 8 + 7] = bfhi(u.w);
    }
    // k rows pre-rotated: reg row s = global row (s + 4*pyh)&7 ; one uint4 per row
    #pragma unroll
    for (int s = 0; s < 8; ++s) {
        int r = (s + 4 * pyh) & 7;
        uint4 u = ((const uint4*)gk)[r];
        k[s * 8 + 0] = bflo(u.x); k[s * 8 + 1] = bfhi(u.x);
        k[s * 8 + 2] = bflo(u.y); k[s * 8 + 3] = bfhi(u.y);
        k[s * 8 + 4] = bflo(u.z); k[s * 8 + 5] = bfhi(u.z);
        k[s * 8 + 6] = bflo(u.w); k[s * 8 + 7] = bfhi(u.w);
    }
    float acc[4][8];
    #pragma unroll
    for (int it = 0; it < 4; ++it)
        #pragma unroll
        for (int px = 0; px < 8; ++px) acc[it][px] = 0.f;
    #pragma unroll
    for (int iy = 0; iy < 8; ++iy)
        #pragma unroll
        for (int ix = 0; ix < 8; ++ix) {
            float qv = q[iy * 8 + ix];
            #pragma unroll
            for (int it = 0; it < 4; ++it) {
                int ks = (it - iy) & 7;              // compile-time
                #pragma unroll
                for (int px = 0; px < 8; ++px)
                    acc[it][px] = fmaf(qv, k[ks * 8 + ((px - ix) & 7)], acc[it][px]);
            }
        }
    // transposed conv scratch: sC[c][pix], pad 68 (row stride 272 B, 16B-aligned)
    #pragma unroll
    for (int it = 0; it < 4; ++it) {
        int pix0 = pyh * 32 + it * 8;
        *(float4*)&sBuf[c * 68 + pix0] =
            make_float4(acc[it][0], acc[it][1], acc[it][2], acc[it][3]);
        *(float4*)&sBuf[c * 68 + pix0 + 4] =
            make_float4(acc[it][4], acc[it][5], acc[it][6], acc[it][7]);
    }
    // prefetch v (32 bf16 = 4 uint4)
    const uint4* gv = (const uint4*)(qkv + ((size_t)(b * 384 + 256 + c)) * QS
                                     + p * 64 + pyh * 32);
    float vv[32];
    #pragma unroll
    for (int f = 0; f < 4; ++f) {
        uint4 u = gv[f];
        vv[f * 8 + 0] = bflo(u.x); vv[f * 8 + 1] = bfhi(u.x);
        vv[f * 8 + 2] = bflo(u.y); vv[f * 8 + 3] = bfhi(u.y);
        vv[f * 8 + 4] = bflo(u.z); vv[f * 8 + 5] = bfhi(u.z);
        vv[f * 8 + 6] = bflo(u.w); vv[f * 8 + 7] = bfhi(u.w);
    }
    float lw = lnw[c], lb = lnb[c];
    __syncthreads();

    // P1: per-pixel channel reduction. Wave w owns pixels w*16..w*16+15;
    // lane bits 4..5 = channel-quarter -> butterfly within the wave.
    {
        int q4 = (t >> 4) & 3;
        int px = (t & 15) | ((t >> 6) << 4);
        float s = 0.f, s2 = 0.f;
        #pragma unroll
        for (int j = 0; j < 32; ++j) {
            float v = sBuf[(q4 * 32 + j) * 68 + px];
            s += v;
            s2 = fmaf(v, v, s2);
        }
        s  += __shfl_xor(s, 16);   s2 += __shfl_xor(s2, 16);
        s  += __shfl_xor(s, 32);   s2 += __shfl_xor(s2, 32);
        if ((t & 48) == 0) {
            float mu = s * (1.f / 128.f);
            float var = s2 * (1.f / 128.f) - mu * mu;
            sMu[px] = mu;
            sRstd[px] = rsqrtf(var + 1e-5f);
        }
    }
    __syncthreads();
    // P3: normalize from acc regs, * v, stage tvv as sT[pix][132] (c contiguous)
    #pragma unroll
    for (int it = 0; it < 4; ++it) {
        int pix0 = pyh * 32 + it * 8;
        float4 ma = *(const float4*)&sMu[pix0];
        float4 mb = *(const float4*)&sMu[pix0 + 4];
        float4 ra = *(const float4*)&sRstd[pix0];
        float4 rb = *(const float4*)&sRstd[pix0 + 4];
        float mus[8] = {ma.x, ma.y, ma.z, ma.w, mb.x, mb.y, mb.z, mb.w};
        float rss[8] = {ra.x, ra.y, ra.z, ra.w, rb.x, rb.y, rb.z, rb.w};
        #pragma unroll
        for (int px = 0; px < 8; ++px) {
            float tv = fmaf((acc[it][px] - mus[px]) * rss[px], lw, lb)
                       * vv[it * 8 + px];
            sBuf[(pix0 + px) * 132 + c] = tv;
        }
    }
    __syncthreads();
    // P4: proj 128->64, tvv read as float4 (4 channels / ds_read_b128)
    {
        int px = t & 63;
        int og = __builtin_amdgcn_readfirstlane((t >> 6) * 16);
        float po[16];
        #pragma unroll
        for (int j = 0; j < 16; ++j) po[j] = 0.f;
        const float4* tb = (const float4*)&sBuf[px * 132];
        #pragma unroll 4
        for (int k4 = 0; k4 < 32; ++k4) {
            float4 tv = tb[k4];
            const float* w0 = wpT + (k4 * 4 + 0) * 64 + og;
            const float* w1 = wpT + (k4 * 4 + 1) * 64 + og;
            const float* w2 = wpT + (k4 * 4 + 2) * 64 + og;
            const float* w3 = wpT + (k4 * 4 + 3) * 64 + og;
            #pragma unroll
            for (int j = 0; j < 16; ++j)
                po[j] = fmaf(w0[j], tv.x,
                        fmaf(w1[j], tv.y,
                        fmaf(w2[j], tv.z,
                        fmaf(w3[j], tv.w, po[j]))));
        }
        int grow = r0 + (p >> 5) * 8 + (px >> 3);
        int gcol = (p & 31) * 8 + (px & 7);
        float* ob = outp + ((size_t)(b * 64 + og)) * HW + grow * 256 + gcol;
        #pragma unroll
        for (int j = 0; j < 16; ++j) ob[(size_t)j * HW] = po[j];
    }
}

extern "C" void kernel_launch(void* const* d_in, const int* in_sizes, int n_in,
                              void* d_out, int out_size, void* d_ws, size_t ws_size,
                              hipStream_t stream) {
    const float* x     = (const float*)d_in[0];
    const float* prior = (const float*)d_in[1];
    const float* wk    = (const float*)d_in[2];
    const float* wh    = (const float*)d_in[3];
    const float* wdw   = (const float*)d_in[4];
    const float* wp    = (const float*)d_in[5];
    const float* lnw   = (const float*)d_in[6];
    const float* lnb   = (const float*)d_in[7];
    float* out = (float*)d_out;
    float* ws  = (float*)d_ws;

    float* kv  = ws;
    float* whT = ws + 512;
    float* wpT = ws + 512 + 24576;
    unsigned short* hid = (unsigned short*)(ws + 40960);        // [4][384][66][256] bf16
    unsigned short* qkv = hid + (size_t)4 * 384 * HSZ2;         // [4][384][256][64] bf16

    k_prep<<<dim3(130), dim3(256), 0, stream>>>(prior, wk, wh, wp, kv, whT, wpT);
    for (int slab = 0; slab < 4; ++slab) {
        int r0 = slab * SLAB;
        k2_hidden<<<dim3(HROWS, 4, 4), dim3(256), 0, stream>>>(x, whT, kv, hid, r0);
        k3_dw<<<dim3(16, 192, 4), dim3(256), 0, stream>>>(hid, wdw, qkv);
        kC_patch<<<dim3(256, 4), dim3(256), 0, stream>>>(qkv, wpT, lnw, lnb, out, r0);
    }
}

// Round 7
// 671.501 us; speedup vs baseline: 1.1194x; 1.0520x over previous
//
#include <hip/hip_runtime.h>

// FSAS slab pipeline, 4 slabs of 64 rows, bf16 intermediates:
//   k2: affine(kv) + 1x1 conv 64->384 -> hid bf16 slab (66 rows incl. halo)
//       (v2 structure: row-pair blocks, 32-ch chunks, acc in unified regs,
//        4 waves/SIMD — best measured 65us/slab)
//   k3: grouped 3x3 -> qkv bf16 slab, PATCHIFIED [ch][patch(256)][64]
//       v2: 32-row x 64-col tiles (2x per-thread work, half the halo overhead)
//   kC: per-patch circular conv (q,k in VGPRs) + LN + *v + proj 128->64 -> out
// Workspace:
//   kv  fp32 @ 0      (512)
//   whT fp32 @ 512    (24576)  whT[c*384+o] = w_hidden[o][c]
//   wpT fp32 @ 25088  (8192)   wpT[c*64+o]  = w_proj[o][c]
//   hid bf16 @ float-ofs 40960 : [4][384][66][256]  (51.9 MB)
//   qkv bf16 after hid          : [4][384][256][64]  (50.3 MB)
// Total 102,400,000 B = 97.66 MiB (< proven 99.15 MiB).

#define HW    65536
#define SLAB  64
#define HROWS 66
#define HSZ2  (HROWS*256)   // bf16 elems per (b,ch) hid plane
#define QS    16384         // bf16 elems per (b,ch) qkv plane (256 patches * 64)

__device__ __forceinline__ unsigned short f2bf(float f) {
    unsigned u = __float_as_uint(f);
    u += 0x7FFFu + ((u >> 16) & 1u);       // RNE
    return (unsigned short)(u >> 16);
}
__device__ __forceinline__ float bflo(unsigned u) { return __uint_as_float(u << 16); }
__device__ __forceinline__ float bfhi(unsigned u) { return __uint_as_float(u & 0xFFFF0000u); }

__global__ void k_prep(const float* __restrict__ prior, const float* __restrict__ wk,
                       const float* __restrict__ wh, const float* __restrict__ wp,
                       float* __restrict__ kv, float* __restrict__ whT, float* __restrict__ wpT) {
    int t = blockIdx.x * 256 + threadIdx.x;
    if (t < 512) {
        int b = t >> 7, k = t & 127;
        const float* p = prior + b * 192;
        const float* w = wk + k * 192;
        float s = 0.f;
        for (int f = 0; f < 192; ++f) s = fmaf(p[f], w[f], s);
        kv[t] = s;
        return;
    }
    t -= 512;
    if (t < 24576) {
        int c = t / 384, o = t - c * 384;
        whT[t] = wh[o * 64 + c];
        return;
    }
    t -= 24576;
    int c = t >> 6, o = t & 63;
    wpT[t] = wp[o * 128 + c];
}

// v2 (proven 65us/slab): thread = row-sub (t>>7) of a row-pair block, col pair
// 2*(t&127). 32 out-ch chunk -> acc 64 regs -> 4 waves/SIMD.
__global__ __launch_bounds__(256, 4) void k2_hidden(const float* __restrict__ x,
    const float* __restrict__ whT, const float* __restrict__ kv,
    unsigned short* __restrict__ hid, int r0) {
    int row = blockIdx.x * 2 + (threadIdx.x >> 7);   // 0..65
    int cp = threadIdx.x & 127;
    int chunk = blockIdx.y;          // 0..11
    int b = blockIdx.z;
    int g = r0 - 1 + row;
    unsigned* hb = (unsigned*)(hid + ((size_t)(b * 384 + chunk * 32)) * HSZ2
                               + row * 256 + cp * 2);
    if (g < 0 || g > 255) {
        #pragma unroll
        for (int j = 0; j < 32; ++j) hb[(size_t)j * (HSZ2 / 2)] = 0u;
        return;
    }
    const float2* xb = (const float2*)(x + (size_t)b * 64 * HW + g * 256 + cp * 2);
    const float* kv1 = kv + b * 128;
    const float* kv2 = kv1 + 64;
    float acc0[32], acc1[32];
    #pragma unroll
    for (int j = 0; j < 32; ++j) { acc0[j] = 0.f; acc1[j] = 0.f; }
    #pragma unroll 4
    for (int c = 0; c < 64; ++c) {
        float2 xv = xb[(size_t)c * (HW / 2)];
        float xp0 = fmaf(xv.x, kv1[c], kv2[c]);
        float xp1 = fmaf(xv.y, kv1[c], kv2[c]);
        const float* wr = whT + c * 384 + chunk * 32;   // wave-uniform -> scalar loads
        #pragma unroll
        for (int j = 0; j < 32; ++j) {
            acc0[j] = fmaf(wr[j], xp0, acc0[j]);
            acc1[j] = fmaf(wr[j], xp1, acc1[j]);
        }
    }
    #pragma unroll
    for (int j = 0; j < 32; ++j)
        hb[(size_t)j * (HSZ2 / 2)] = (unsigned)f2bf(acc0[j]) | ((unsigned)f2bf(acc1[j]) << 16);
}

// grouped 3x3 conv from bf16 hid -> bf16 qkv patchified [ch][patch][py*8+px]
// v2: 32-row x 64-col tile per block (halo 34x66), 4 pp-passes, 288 fma/thread.
__global__ __launch_bounds__(256) void k3_dw(const unsigned short* __restrict__ hid,
    const float* __restrict__ wdw, unsigned short* __restrict__ qkv) {
    __shared__ float sIn[2 * 34 * 66];
    int t = threadIdx.x;
    int bid = blockIdx.x;            // 8 tiles: tx 0..3 (x64 cols), ty 0..1 (x32 rows)
    int gl = blockIdx.y;             // 0..191
    int b = blockIdx.z;
    int tx = bid & 3, ty = bid >> 2;
    int x0 = tx * 64, y0 = ty * 32;
    const unsigned short* hbase = hid + ((size_t)(b * 384 + 2 * gl)) * HSZ2;
    for (int idx = t; idx < 2 * 34 * 66; idx += 256) {
        int chl = idx >= 2244;
        int rem = idx - chl * 2244;
        int row = rem / 66;
        int col = rem - row * 66;
        int gx = x0 + col - 1;
        float v = 0.f;
        if (gx >= 0 && gx < 256)
            v = bflo((unsigned)hbase[(size_t)chl * HSZ2 + (y0 + row) * 256 + gx]);
        sIn[idx] = v;
    }
    __syncthreads();
    int og = 2 * gl;
    float w0[18], w1[18];
    #pragma unroll
    for (int i = 0; i < 18; ++i) {
        w0[i] = wdw[(size_t)og * 18 + i];
        w1[i] = wdw[(size_t)(og + 1) * 18 + i];
    }
    unsigned short* q0 = qkv + ((size_t)(b * 384 + og)) * QS;
    #pragma unroll
    for (int pp = 0; pp < 4; ++pp) {
        int ly = pp * 8 + (t >> 5);                  // 0..31
        int lxp = (t & 31) * 2;                      // even col in tile
        float a[2][2];                               // [px][out-ch]
        #pragma unroll
        for (int px = 0; px < 2; ++px) {
            float s0 = 0.f, s1 = 0.f;
            #pragma unroll
            for (int i = 0; i < 2; ++i)
                #pragma unroll
                for (int ky = 0; ky < 3; ++ky)
                    #pragma unroll
                    for (int kx = 0; kx < 3; ++kx) {
                        float v = sIn[i * 2244 + (ly + ky) * 66 + (lxp + px + kx)];
                        s0 = fmaf(w0[i * 9 + ky * 3 + kx], v, s0);
                        s1 = fmaf(w1[i * 9 + ky * 3 + kx], v, s1);
                    }
            a[px][0] = s0; a[px][1] = s1;
        }
        int row = y0 + ly;                           // slab row 0..63
        int gx = x0 + lxp;
        int patch = (row >> 3) * 32 + (gx >> 3);     // 0..255
        int off = patch * 64 + (row & 7) * 8 + (gx & 7);   // even
        ((unsigned*)(q0 + off))[0] =
            (unsigned)f2bf(a[0][0]) | ((unsigned)f2bf(a[1][0]) << 16);
        ((unsigned*)(q0 + QS + off))[0] =
            (unsigned)f2bf(a[0][1]) | ((unsigned)f2bf(a[1][1]) << 16);
    }
}

// Fused per-patch: circular conv (q,k in regs) + LN(128) + *v + proj 128->64.
// Thread t: channel c = t&127, py-half pyh = t>>7.
// v2 dataflow: 3 barriers, no serial phase.
//   P0 conv -> sC[c][68] (float4 writes, transposed)
//   P1 reduce over c: (q4,px) mapping, 4 partials per pixel live in ONE wave,
//      combined with 2x shfl_xor -> sMu/sRstd (no sRed arrays, no t<64 phase)
//   P3 normalize from acc regs -> tvv to sT[pix][132] (aliases sC)
//   P4 proj: ds_read_b128 over channels (4/instr), weights via SGPR
__global__ __launch_bounds__(256, 2) void kC_patch(const unsigned short* __restrict__ qkv,
    const float* __restrict__ wpT, const float* __restrict__ lnw,
    const float* __restrict__ lnb, float* __restrict__ outp, int r0) {
    __shared__ __align__(16) float sBuf[128 * 68];   // P0/P1: sC[c][68]; P3/P4: sT[pix][132]
    __shared__ __align__(16) float sMu[64];
    __shared__ __align__(16) float sRstd[64];
    int t = threadIdx.x;
    int p = blockIdx.x;              // slab-local patch 0..255
    int b = blockIdx.y;
    int c = t & 127;
    int pyh = t >> 7;

    const uint4* gq = (const uint4*)(qkv + ((size_t)(b * 384 + c)) * QS + p * 64);
    const uint4* gk = (const uint4*)(qkv + ((size_t)(b * 384 + 128 + c)) * QS + p * 64);
    float q[64], k[64];
    #pragma unroll
    for (int f = 0; f < 8; ++f) {                     // 8 bf16 per uint4
        uint4 u = gq[f];
        q[f * 8 + 0] = bflo(u.x); q[f * 8 + 1] = bfhi(u.x);
        q[f * 8 + 2] = bflo(u.y); q[f * 8 + 3] = bfhi(u.y);
        q[f * 8 + 4] = bflo(u.z); q[f * 8 + 5] = bfhi(u.z);
        q[f * 8 + 6] = bflo(u.w); q[f * 8 + 7] = bfhi(u.w);
    }
    // k rows pre-rotated: reg row s = global row (s + 4*pyh)&7 ; one uint4 per row
    #pragma unroll
    for (int s = 0; s < 8; ++s) {
        int r = (s + 4 * pyh) & 7;
        uint4 u = ((const uint4*)gk)[r];
        k[s * 8 + 0] = bflo(u.x); k[s * 8 + 1] = bfhi(u.x);
        k[s * 8 + 2] = bflo(u.y); k[s * 8 + 3] = bfhi(u.y);
        k[s * 8 + 4] = bflo(u.z); k[s * 8 + 5] = bfhi(u.z);
        k[s * 8 + 6] = bflo(u.w); k[s * 8 + 7] = bfhi(u.w);
    }
    float acc[4][8];
    #pragma unroll
    for (int it = 0; it < 4; ++it)
        #pragma unroll
        for (int px = 0; px < 8; ++px) acc[it][px] = 0.f;
    #pragma unroll
    for (int iy = 0; iy < 8; ++iy)
        #pragma unroll
        for (int ix = 0; ix < 8; ++ix) {
            float qv = q[iy * 8 + ix];
            #pragma unroll
            for (int it = 0; it < 4; ++it) {
                int ks = (it - iy) & 7;              // compile-time
                #pragma unroll
                for (int px = 0; px < 8; ++px)
                    acc[it][px] = fmaf(qv, k[ks * 8 + ((px - ix) & 7)], acc[it][px]);
            }
        }
    // transposed conv scratch: sC[c][pix], pad 68 (row stride 272 B, 16B-aligned)
    #pragma unroll
    for (int it = 0; it < 4; ++it) {
        int pix0 = pyh * 32 + it * 8;
        *(float4*)&sBuf[c * 68 + pix0] =
            make_float4(acc[it][0], acc[it][1], acc[it][2], acc[it][3]);
        *(float4*)&sBuf[c * 68 + pix0 + 4] =
            make_float4(acc[it][4], acc[it][5], acc[it][6], acc[it][7]);
    }
    // prefetch v (32 bf16 = 4 uint4)
    const uint4* gv = (const uint4*)(qkv + ((size_t)(b * 384 + 256 + c)) * QS
                                     + p * 64 + pyh * 32);
    float vv[32];
    #pragma unroll
    for (int f = 0; f < 4; ++f) {
        uint4 u = gv[f];
        vv[f * 8 + 0] = bflo(u.x); vv[f * 8 + 1] = bfhi(u.x);
        vv[f * 8 + 2] = bflo(u.y); vv[f * 8 + 3] = bfhi(u.y);
        vv[f * 8 + 4] = bflo(u.z); vv[f * 8 + 5] = bfhi(u.z);
        vv[f * 8 + 6] = bflo(u.w); vv[f * 8 + 7] = bfhi(u.w);
    }
    float lw = lnw[c], lb = lnb[c];
    __syncthreads();

    // P1: per-pixel channel reduction. Wave w owns pixels w*16..w*16+15;
    // lane bits 4..5 = channel-quarter -> butterfly within the wave.
    {
        int q4 = (t >> 4) & 3;
        int px = (t & 15) | ((t >> 6) << 4);
        float s = 0.f, s2 = 0.f;
        #pragma unroll
        for (int j = 0; j < 32; ++j) {
            float v = sBuf[(q4 * 32 + j) * 68 + px];
            s += v;
            s2 = fmaf(v, v, s2);
        }
        s  += __shfl_xor(s, 16);   s2 += __shfl_xor(s2, 16);
        s  += __shfl_xor(s, 32);   s2 += __shfl_xor(s2, 32);
        if ((t & 48) == 0) {
            float mu = s * (1.f / 128.f);
            float var = s2 * (1.f / 128.f) - mu * mu;
            sMu[px] = mu;
            sRstd[px] = rsqrtf(var + 1e-5f);
        }
    }
    __syncthreads();
    // P3: normalize from acc regs, * v, stage tvv as sT[pix][132] (c contiguous)
    #pragma unroll
    for (int it = 0; it < 4; ++it) {
        int pix0 = pyh * 32 + it * 8;
        float4 ma = *(const float4*)&sMu[pix0];
        float4 mb = *(const float4*)&sMu[pix0 + 4];
        float4 ra = *(const float4*)&sRstd[pix0];
        float4 rb = *(const float4*)&sRstd[pix0 + 4];
        float mus[8] = {ma.x, ma.y, ma.z, ma.w, mb.x, mb.y, mb.z, mb.w};
        float rss[8] = {ra.x, ra.y, ra.z, ra.w, rb.x, rb.y, rb.z, rb.w};
        #pragma unroll
        for (int px = 0; px < 8; ++px) {
            float tv = fmaf((acc[it][px] - mus[px]) * rss[px], lw, lb)
                       * vv[it * 8 + px];
            sBuf[(pix0 + px) * 132 + c] = tv;
        }
    }
    __syncthreads();
    // P4: proj 128->64, tvv read as float4 (4 channels / ds_read_b128)
    {
        int px = t & 63;
        int og = __builtin_amdgcn_readfirstlane((t >> 6) * 16);
        float po[16];
        #pragma unroll
        for (int j = 0; j < 16; ++j) po[j] = 0.f;
        const float4* tb = (const float4*)&sBuf[px * 132];
        #pragma unroll 4
        for (int k4 = 0; k4 < 32; ++k4) {
            float4 tv = tb[k4];
            const float* w0 = wpT + (k4 * 4 + 0) * 64 + og;
            const float* w1 = wpT + (k4 * 4 + 1) * 64 + og;
            const float* w2 = wpT + (k4 * 4 + 2) * 64 + og;
            const float* w3 = wpT + (k4 * 4 + 3) * 64 + og;
            #pragma unroll
            for (int j = 0; j < 16; ++j)
                po[j] = fmaf(w0[j], tv.x,
                        fmaf(w1[j], tv.y,
                        fmaf(w2[j], tv.z,
                        fmaf(w3[j], tv.w, po[j]))));
        }
        int grow = r0 + (p >> 5) * 8 + (px >> 3);
        int gcol = (p & 31) * 8 + (px & 7);
        float* ob = outp + ((size_t)(b * 64 + og)) * HW + grow * 256 + gcol;
        #pragma unroll
        for (int j = 0; j < 16; ++j) ob[(size_t)j * HW] = po[j];
    }
}

extern "C" void kernel_launch(void* const* d_in, const int* in_sizes, int n_in,
                              void* d_out, int out_size, void* d_ws, size_t ws_size,
                              hipStream_t stream) {
    const float* x     = (const float*)d_in[0];
    const float* prior = (const float*)d_in[1];
    const float* wk    = (const float*)d_in[2];
    const float* wh    = (const float*)d_in[3];
    const float* wdw   = (const float*)d_in[4];
    const float* wp    = (const float*)d_in[5];
    const float* lnw   = (const float*)d_in[6];
    const float* lnb   = (const float*)d_in[7];
    float* out = (float*)d_out;
    float* ws  = (float*)d_ws;

    float* kv  = ws;
    float* whT = ws + 512;
    float* wpT = ws + 512 + 24576;
    unsigned short* hid = (unsigned short*)(ws + 40960);        // [4][384][66][256] bf16
    unsigned short* qkv = hid + (size_t)4 * 384 * HSZ2;         // [4][384][256][64] bf16

    k_prep<<<dim3(130), dim3(256), 0, stream>>>(prior, wk, wh, wp, kv, whT, wpT);
    for (int slab = 0; slab < 4; ++slab) {
        int r0 = slab * SLAB;
        k2_hidden<<<dim3(HROWS / 2, 12, 4), dim3(256), 0, stream>>>(x, whT, kv, hid, r0);
        k3_dw<<<dim3(8, 192, 4), dim3(256), 0, stream>>>(hid, wdw, qkv);
        kC_patch<<<dim3(256, 4), dim3(256), 0, stream>>>(qkv, wpT, lnw, lnb, out, r0);
    }
}